// Round 1
// baseline (144.826 us; speedup 1.0000x reference)
//
#include <hip/hip_runtime.h>

// TV loss via exact spatial-domain identity of the FFT pipeline:
//   gx[y,x] = in[y,x] - in[y,(x+1)%W]
//   gy[y,x] = in[y,x] - in[(y+1)%H,x]
//   result  = sum(sqrt(gx^2 + gy^2)) / (B*C*H*W)
// Shapes fixed by setup_inputs(): B=32, C=3, H=512, W=512 (fp32).

#define DIM_H 512
#define DIM_W 512
#define PLANES 96                       // B*C
#define TOTAL (PLANES * DIM_H * DIM_W)  // 25165824 elements
#define NV (TOTAL / 4)                  // 6291456 float4 units
#define NBLOCKS 2048
#define NTHREADS 256

__global__ __launch_bounds__(NTHREADS) void tv_partial(const float* __restrict__ in,
                                                       float* __restrict__ partial) {
    const float4* __restrict__ in4 = (const float4*)in;
    int tid = blockIdx.x * NTHREADS + threadIdx.x;
    float s = 0.0f;

    for (int i = tid; i < NV; i += NBLOCKS * NTHREADS) {
        // decompose: plane p, row y, float4-column x4  (W/4 = 128, H*W/4 = 65536)
        int p  = i >> 16;        // / 65536
        int r  = i & 65535;
        int y  = r >> 7;         // / 128
        int x4 = r & 127;

        float4 c = in4[i];

        // down neighbor row (circular)
        int ydn = (y + 1) & (DIM_H - 1);
        float4 d = in4[(p << 16) | (ydn << 7) | x4];

        // right-wrap scalar element: in[p][y][(4*x4+4) % 512]
        int xw = ((x4 << 2) + 4) & (DIM_W - 1);
        float e = in[(p << 18) + (y << 9) + xw];

        float dx0 = c.x - c.y, dy0 = c.x - d.x;
        float dx1 = c.y - c.z, dy1 = c.y - d.y;
        float dx2 = c.z - c.w, dy2 = c.z - d.z;
        float dx3 = c.w - e,   dy3 = c.w - d.w;

        s += sqrtf(dx0 * dx0 + dy0 * dy0);
        s += sqrtf(dx1 * dx1 + dy1 * dy1);
        s += sqrtf(dx2 * dx2 + dy2 * dy2);
        s += sqrtf(dx3 * dx3 + dy3 * dy3);
    }

    // wave (64-lane) reduction
    #pragma unroll
    for (int off = 32; off > 0; off >>= 1)
        s += __shfl_down(s, off, 64);

    __shared__ float smem[NTHREADS / 64];
    int lane = threadIdx.x & 63;
    int wave = threadIdx.x >> 6;
    if (lane == 0) smem[wave] = s;
    __syncthreads();
    if (threadIdx.x == 0)
        partial[blockIdx.x] = smem[0] + smem[1] + smem[2] + smem[3];
}

__global__ __launch_bounds__(256) void tv_final(const float* __restrict__ partial,
                                                float* __restrict__ out) {
    float s = 0.0f;
    for (int i = threadIdx.x; i < NBLOCKS; i += 256)
        s += partial[i];

    #pragma unroll
    for (int off = 32; off > 0; off >>= 1)
        s += __shfl_down(s, off, 64);

    __shared__ float smem[4];
    int lane = threadIdx.x & 63;
    int wave = threadIdx.x >> 6;
    if (lane == 0) smem[wave] = s;
    __syncthreads();
    if (threadIdx.x == 0)
        out[0] = (smem[0] + smem[1] + smem[2] + smem[3]) * (1.0f / (float)TOTAL);
}

extern "C" void kernel_launch(void* const* d_in, const int* in_sizes, int n_in,
                              void* d_out, int out_size, void* d_ws, size_t ws_size,
                              hipStream_t stream) {
    const float* in = (const float*)d_in[0];
    float* out = (float*)d_out;
    float* partial = (float*)d_ws;  // NBLOCKS floats of scratch

    tv_partial<<<NBLOCKS, NTHREADS, 0, stream>>>(in, partial);
    tv_final<<<1, 256, 0, stream>>>(partial, out);
}